// Round 9
// baseline (747.960 us; speedup 1.0000x reference)
//
#include <hip/hip_runtime.h>

// SSIM3D, (4,1,128,128,128) fp32, separable 11-tap Gaussian, scalar mean out.
//
// FUSED single-pass (R8 structure, bugs fixed):
//  - workgroup 1024 thr owns (x=128, y-tile=8), walks 42 z-steps with
//    per-thread sliding z-accumulators acc[5][11]. No field intermediate.
//  - R8 bug 1: VGPR cap = 256/w (empirical: R2/R3/R6/R8) -> attr(4,4) gave
//    64 regs + spills (1.97 GB scratch traffic). Now __launch_bounds__(1024,2)
//    => cap 128 (1024-thr block needs <=128 anyway; live set ~100).
//  - R8 bug 2: xy[18][128][6] = 24 B lane stride = 4-6-way bank conflicts
//    (1.97e7). Now field-planar float2/float planes, lane stride 8/4 B,
//    wave-uniform row => conflict-free; 33 LDS insts/step vs 55.
//  - double-buffered planes (92 KB) => ONE barrier per z-step (write buf
//    step&1; barrier; read. Step-s reads complete before step-s+2 writes
//    because they precede the step-s+1 barrier in program order).

#define SLICE (128*128)        // 16384
#define S  (128*SLICE)         // 2097152 per batch item
#define C1_ 0.0001f
#define C2_ 0.0009f

__device__ __forceinline__ void make_g(float* g) {
    float s = 0.f;
#pragma unroll
    for (int i = 0; i < 11; ++i) {
        float d = (float)(i - 5);
        g[i] = __expf(-d * d / 4.5f);
        s += g[i];
    }
    float inv = 1.f / s;
#pragma unroll
    for (int i = 0; i < 11; ++i) g[i] *= inv;
}

// grid: 4n * 16yt * 4zt = 256 blocks of 1024 threads (16 waves, 1 block/CU).
// thread: x = tid&127 (fixed), yl = tid>>7 in 0..7 (output y = yt*8 + yl).
// Wave-uniform: yl is constant within each wave (2 waves per y-row).
__global__ __launch_bounds__(1024, 2)
void ssim_fused(const float* __restrict__ img1, const float* __restrict__ img2,
                float* __restrict__ partials) {
    // double-buffered field-planar LDS: 2*18*128*(8+8+4) B = 90 KB
    __shared__ float2 P01[2][18][128];   // (mu1-pre, mu2-pre)
    __shared__ float2 P23[2][18][128];   // (E11-pre, E22-pre)
    __shared__ float  P4 [2][18][128];   // (E12-pre)
    __shared__ float  redbuf[16];

    float g[11]; make_g(g);
    const int tid = threadIdx.x;
    const int x = tid & 127, yl = tid >> 7;
    const int b = blockIdx.x;
    const int zt = b & 3, yt = (b >> 2) & 15, n = b >> 6;
    const int z0 = zt * 32, y0 = yt * 8;
    const float* p1 = img1 + (size_t)n * S;
    const float* p2 = img2 + (size_t)n * S;

    // even-aligned x-window (R7/R8-proven): 7 float2 loads at cols s0-6+2m,
    // per-parity shifted 14-tap weights, boundary taps zeroed.
    const int odd = x & 1, s0 = x & ~1;
    float w14[14];
#pragma unroll
    for (int j = 0; j < 14; ++j) {
        int c = s0 - 6 + j;
        bool cok = (c >= 0) && (c < 128);
        float we = (j >= 1 && j <= 11 && cok) ? g[j - 1] : 0.f;  // even x
        float wo = (j >= 2 && j <= 12 && cok) ? g[j - 2] : 0.f;  // odd x
        w14[j] = odd ? wo : we;
    }
    int cc[7];
#pragma unroll
    for (int m = 0; m < 7; ++m)
        cc[m] = min(max(s0 - 6 + 2 * m, 0), 126);

    float acc[5][11];
#pragma unroll
    for (int f = 0; f < 5; ++f)
#pragma unroll
        for (int s2 = 0; s2 < 11; ++s2) acc[f][s2] = 0.f;

    float sum = 0.f;

    // x-conv one y-halo row of slice zoff -> LDS planes (buffer p)
    auto xconv_row = [&](int r, int p, size_t zoff) {
        int y_in = y0 - 5 + r;
        int y_cl = min(max(y_in, 0), 127);
        float msk = (y_in >= 0 && y_in < 128) ? 1.f : 0.f;
        const float* ra = p1 + zoff + (size_t)y_cl * 128;
        const float* rb = p2 + zoff + (size_t)y_cl * 128;
        float u1 = 0, u2 = 0, a11 = 0, a22 = 0, a12 = 0;
#pragma unroll
        for (int m = 0; m < 7; ++m) {
            float2 A2 = *(const float2*)(ra + cc[m]);
            float2 B2 = *(const float2*)(rb + cc[m]);
            {
                float wj = w14[2 * m];
                float ta = wj * A2.x, tb = wj * B2.x;
                u1 += ta; u2 += tb;
                a11 = fmaf(ta, A2.x, a11);
                a12 = fmaf(ta, B2.x, a12);
                a22 = fmaf(tb, B2.x, a22);
            }
            {
                float wj = w14[2 * m + 1];
                float ta = wj * A2.y, tb = wj * B2.y;
                u1 += ta; u2 += tb;
                a11 = fmaf(ta, A2.y, a11);
                a12 = fmaf(ta, B2.y, a12);
                a22 = fmaf(tb, B2.y, a22);
            }
        }
        P01[p][r][x] = make_float2(u1 * msk, u2 * msk);
        P23[p][r][x] = make_float2(a11 * msk, a22 * msk);
        P4 [p][r][x] = a12 * msk;
    };

#pragma unroll 1
    for (int blk = 0; blk < 4; ++blk) {
#pragma unroll
        for (int t = 0; t < 11; ++t) {
            const int step = blk * 11 + t;
            if (step >= 42) continue;                // uniform skip (last 2)
            const int p = step & 1;
            const int z_in = z0 + step - 5;
            const int z_cl = min(max(z_in, 0), 127);
            const bool zok = (z_in >= 0) && (z_in < 128);
            const size_t zoff = (size_t)z_cl * SLICE;

            // ---- stage 1: x-conv the 18 y-halo rows of slice z_in
            xconv_row(yl, p, zoff);
            xconv_row(yl + 8, p, zoff);
            if (yl < 2) xconv_row(16 + yl, p, zoff); // wave-uniform branch
            __syncthreads();                         // planes[p] complete

            // ---- stage 2: y-conv gather (rows yl..yl+10) + z-slide
            float v0 = 0, v1 = 0, v2 = 0, v3 = 0, v4 = 0;
#pragma unroll
            for (int k = 0; k < 11; ++k) {
                float2 q01 = P01[p][yl + k][x];
                float2 q23 = P23[p][yl + k][x];
                float  q4  = P4 [p][yl + k][x];
                float wk = g[k];
                v0 = fmaf(wk, q01.x, v0);
                v1 = fmaf(wk, q01.y, v1);
                v2 = fmaf(wk, q23.x, v2);
                v3 = fmaf(wk, q23.y, v3);
                v4 = fmaf(wk, q4,    v4);
            }
#pragma unroll
            for (int j = 0; j < 11; ++j) {
                int oo = step - 10 + j;
                float wz = (zok && oo >= 0 && oo < 32) ? g[10 - j] : 0.f;
                const int sl = (t + j + 1) % 11;     // static under unroll
                acc[0][sl] = fmaf(wz, v0, acc[0][sl]);
                acc[1][sl] = fmaf(wz, v1, acc[1][sl]);
                acc[2][sl] = fmaf(wz, v2, acc[2][sl]);
                acc[3][sl] = fmaf(wz, v3, acc[3][sl]);
                acc[4][sl] = fmaf(wz, v4, acc[4][sl]);
            }
            if (step >= 10) {
                const int es = (t + 1) % 11;         // static
                float m1 = acc[0][es], m2 = acc[1][es];
                float p11 = acc[2][es], p22 = acc[3][es];
                float p12 = acc[4][es];
                float m1s = m1 * m1, m2s = m2 * m2, m12 = m1 * m2;
                float vv1 = p11 - m1s, vv2 = p22 - m2s, cv = p12 - m12;
                float num = (2.f * m12 + C1_) * (2.f * cv + C2_);
                float den = (m1s + m2s + C1_) * (vv1 + vv2 + C2_);
                sum += num / den;
#pragma unroll
                for (int f = 0; f < 5; ++f) acc[f][es] = 0.f;
            }
            // no second barrier: next step writes buffer p^1; reads of
            // buffer p^1 from step-1 finished before THIS step's barrier.
        }
    }

    // ---- block reduction: 16 waves -> 1 value
#pragma unroll
    for (int o = 32; o > 0; o >>= 1) sum += __shfl_down(sum, o, 64);
    if ((tid & 63) == 0) redbuf[tid >> 6] = sum;
    __syncthreads();
    if (tid < 64) {
        float s2 = (tid < 16) ? redbuf[tid] : 0.f;
#pragma unroll
        for (int o = 8; o > 0; o >>= 1) s2 += __shfl_down(s2, o, 64);
        if (tid == 0) partials[b] = s2;
    }
}

// ---------------- final reduce of 256 partials ----------------
__global__ void ssim_final(const float* __restrict__ partial, int nPart,
                           float* __restrict__ out, double inv_count) {
    int tid = threadIdx.x;
    double s = 0.0;
    for (int i = tid; i < nPart; i += 256) s += (double)partial[i];
#pragma unroll
    for (int o = 32; o > 0; o >>= 1) s += __shfl_down(s, o, 64);
    __shared__ double wsum[4];
    int lane = tid & 63, wid = tid >> 6;
    if (lane == 0) wsum[wid] = s;
    __syncthreads();
    if (tid == 0)
        out[0] = (float)((wsum[0] + wsum[1] + wsum[2] + wsum[3]) * inv_count);
}

extern "C" void kernel_launch(void* const* d_in, const int* in_sizes, int n_in,
                              void* d_out, int out_size, void* d_ws, size_t ws_size,
                              hipStream_t stream) {
    const float* img1 = (const float*)d_in[0];
    const float* img2 = (const float*)d_in[1];
    float* out = (float*)d_out;
    float* partials = (float*)d_ws;                  // 256 floats

    ssim_fused<<<256, 1024, 0, stream>>>(img1, img2, partials);
    ssim_final<<<1, 256, 0, stream>>>(partials, 256, out,
                                      1.0 / ((double)S * 4));
}

// Round 10
// 399.343 us; speedup vs baseline: 1.8730x; 1.8730x over previous
//
#include <hip/hip_runtime.h>

// SSIM3D, (4,1,128,128,128) fp32, separable 11-tap Gaussian, scalar mean out.
//
// FUSED single-pass, 512-thread blocks (R9 post-mortem: 1024-thr blocks pin
// the allocator at 64 VGPR -> ~1 GB spill traffic; 512-thr + lb(512,2) is
// the config both empirical allocator models give a 128-reg cap for).
//
// Block owns (x=128, y-tile=4), walks 42 z-steps. Per step:
//   stage1: x-conv the 14 y-halo rows of slice z_in (global float2 loads,
//           L1-hot, even-aligned + per-parity shifted weights) -> LDS planes
//   stage2: y-conv (11 planar LDS reads, conflict-free strides) -> z-sliding
//           accumulators acc[5][11] (regs) -> SSIM -> running sum.
// Double-buffered planes (71.7 KB, 2 blocks/CU) => ONE barrier per step.
// Gaussian taps are fp32 literals (frees 11 VGPRs; error ~1e-8 << 1e-3 tol).

#define SLICE (128*128)        // 16384
#define S  (128*SLICE)         // 2097152 per batch item
#define C1_ 0.0001f
#define C2_ 0.0009f

// 11-tap Gaussian, sigma=1.5, normalized (standard SSIM window, fp32)
#define G0 0.00102838f
#define G1 0.00759876f
#define G2 0.03600077f
#define G3 0.10936069f
#define G4 0.21300553f
#define G5 0.26601172f

// grid: 4n * 32yt * 4zt = 512 blocks of 512 threads (8 waves, 2 blocks/CU).
// thread: x = tid&127 (fixed), tr = tid>>7 in 0..3 (output y = yt*4 + tr).
// tr is wave-uniform (wave = 64 consecutive tids).
__global__ __launch_bounds__(512, 2)
void ssim_fused(const float* __restrict__ img1, const float* __restrict__ img2,
                float* __restrict__ partials) {
    // double-buffered field-planar LDS: 2*14*128*(8+8+4) B = 71.7 KB
    __shared__ float2 P01[2][14][128];   // (mu1-pre, mu2-pre)
    __shared__ float2 P23[2][14][128];   // (E11-pre, E22-pre)
    __shared__ float  P4 [2][14][128];   // (E12-pre)
    __shared__ float  redbuf[8];

    const float g[11] = {G0,G1,G2,G3,G4,G5,G4,G3,G2,G1,G0};
    const int tid = threadIdx.x;
    const int x = tid & 127, tr = tid >> 7;
    const int b = blockIdx.x;
    const int zt = b & 3, yt = (b >> 2) & 31, n = b >> 7;
    const int z0 = zt * 32, y0 = yt * 4;
    const float* p1 = img1 + (size_t)n * S;
    const float* p2 = img2 + (size_t)n * S;

    // even-aligned x-window (R7-proven): 7 float2 loads at cols s0-6+2m,
    // per-parity shifted 14-tap weights, boundary taps zeroed.
    const int odd = x & 1, s0 = x & ~1;
    float w14[14];
#pragma unroll
    for (int j = 0; j < 14; ++j) {
        int c = s0 - 6 + j;
        bool cok = (c >= 0) && (c < 128);
        float we = (j >= 1 && j <= 11 && cok) ? g[j - 1] : 0.f;  // even x
        float wo = (j >= 2 && j <= 12 && cok) ? g[j - 2] : 0.f;  // odd x
        w14[j] = odd ? wo : we;
    }
    int cc[7];
#pragma unroll
    for (int m = 0; m < 7; ++m)
        cc[m] = min(max(s0 - 6 + 2 * m, 0), 126);

    float acc[5][11];
#pragma unroll
    for (int f = 0; f < 5; ++f)
#pragma unroll
        for (int s2 = 0; s2 < 11; ++s2) acc[f][s2] = 0.f;

    float sum = 0.f;

    // x-conv one y-halo row (r in 0..13) of slice zoff -> LDS planes buf p
    auto xconv_row = [&](int r, int p, size_t zoff) {
        int y_in = y0 - 5 + r;
        int y_cl = min(max(y_in, 0), 127);
        float msk = (y_in >= 0 && y_in < 128) ? 1.f : 0.f;
        const float* ra = p1 + zoff + (size_t)y_cl * 128;
        const float* rb = p2 + zoff + (size_t)y_cl * 128;
        float u1 = 0, u2 = 0, a11 = 0, a22 = 0, a12 = 0;
#pragma unroll
        for (int m = 0; m < 7; ++m) {
            float2 A2 = *(const float2*)(ra + cc[m]);
            float2 B2 = *(const float2*)(rb + cc[m]);
            {
                float wj = w14[2 * m];
                float ta = wj * A2.x, tb = wj * B2.x;
                u1 += ta; u2 += tb;
                a11 = fmaf(ta, A2.x, a11);
                a12 = fmaf(ta, B2.x, a12);
                a22 = fmaf(tb, B2.x, a22);
            }
            {
                float wj = w14[2 * m + 1];
                float ta = wj * A2.y, tb = wj * B2.y;
                u1 += ta; u2 += tb;
                a11 = fmaf(ta, A2.y, a11);
                a12 = fmaf(ta, B2.y, a12);
                a22 = fmaf(tb, B2.y, a22);
            }
        }
        P01[p][r][x] = make_float2(u1 * msk, u2 * msk);
        P23[p][r][x] = make_float2(a11 * msk, a22 * msk);
        P4 [p][r][x] = a12 * msk;
    };

#pragma unroll 1
    for (int blk = 0; blk < 4; ++blk) {
#pragma unroll
        for (int t = 0; t < 11; ++t) {
            const int step = blk * 11 + t;
            if (step >= 42) continue;                // uniform skip (last 2)
            const int p = step & 1;
            const int z_in = z0 + step - 5;
            const int z_cl = min(max(z_in, 0), 127);
            const bool zok = (z_in >= 0) && (z_in < 128);
            const size_t zoff = (size_t)z_cl * SLICE;

            // ---- stage 1: x-conv the 14 y-halo rows of slice z_in
            xconv_row(tr, p, zoff);
            xconv_row(tr + 4, p, zoff);
            xconv_row(tr + 8, p, zoff);
            if (tr < 2) xconv_row(tr + 12, p, zoff); // wave-uniform branch
            __syncthreads();                         // planes[p] complete

            // ---- stage 2: y-conv gather (rows tr..tr+10) + z-slide
            float v0 = 0, v1 = 0, v2 = 0, v3 = 0, v4 = 0;
#pragma unroll
            for (int k = 0; k < 11; ++k) {
                float2 q01 = P01[p][tr + k][x];
                float2 q23 = P23[p][tr + k][x];
                float  q4  = P4 [p][tr + k][x];
                float wk = g[k];
                v0 = fmaf(wk, q01.x, v0);
                v1 = fmaf(wk, q01.y, v1);
                v2 = fmaf(wk, q23.x, v2);
                v3 = fmaf(wk, q23.y, v3);
                v4 = fmaf(wk, q4,    v4);
            }
#pragma unroll
            for (int j = 0; j < 11; ++j) {
                int oo = step - 10 + j;
                float wz = (zok && oo >= 0 && oo < 32) ? g[10 - j] : 0.f;
                const int sl = (t + j + 1) % 11;     // static under unroll
                acc[0][sl] = fmaf(wz, v0, acc[0][sl]);
                acc[1][sl] = fmaf(wz, v1, acc[1][sl]);
                acc[2][sl] = fmaf(wz, v2, acc[2][sl]);
                acc[3][sl] = fmaf(wz, v3, acc[3][sl]);
                acc[4][sl] = fmaf(wz, v4, acc[4][sl]);
            }
            if (step >= 10) {
                const int es = (t + 1) % 11;         // static
                float m1 = acc[0][es], m2 = acc[1][es];
                float p11 = acc[2][es], p22 = acc[3][es];
                float p12 = acc[4][es];
                float m1s = m1 * m1, m2s = m2 * m2, m12 = m1 * m2;
                float vv1 = p11 - m1s, vv2 = p22 - m2s, cv = p12 - m12;
                float num = (2.f * m12 + C1_) * (2.f * cv + C2_);
                float den = (m1s + m2s + C1_) * (vv1 + vv2 + C2_);
                sum += num / den;
#pragma unroll
                for (int f = 0; f < 5; ++f) acc[f][es] = 0.f;
            }
            // no 2nd barrier: next step writes buffer p^1, whose readers
            // finished before THIS step's barrier (program order).
        }
    }

    // ---- block reduction: 8 waves -> 1 value
#pragma unroll
    for (int o = 32; o > 0; o >>= 1) sum += __shfl_down(sum, o, 64);
    if ((tid & 63) == 0) redbuf[tid >> 6] = sum;
    __syncthreads();
    if (tid < 64) {
        float s2 = (tid < 8) ? redbuf[tid] : 0.f;
#pragma unroll
        for (int o = 4; o > 0; o >>= 1) s2 += __shfl_down(s2, o, 64);
        if (tid == 0) partials[b] = s2;
    }
}

// ---------------- final reduce of 512 partials ----------------
__global__ void ssim_final(const float* __restrict__ partial, int nPart,
                           float* __restrict__ out, double inv_count) {
    int tid = threadIdx.x;
    double s = 0.0;
    for (int i = tid; i < nPart; i += 256) s += (double)partial[i];
#pragma unroll
    for (int o = 32; o > 0; o >>= 1) s += __shfl_down(s, o, 64);
    __shared__ double wsum[4];
    int lane = tid & 63, wid = tid >> 6;
    if (lane == 0) wsum[wid] = s;
    __syncthreads();
    if (tid == 0)
        out[0] = (float)((wsum[0] + wsum[1] + wsum[2] + wsum[3]) * inv_count);
}

extern "C" void kernel_launch(void* const* d_in, const int* in_sizes, int n_in,
                              void* d_out, int out_size, void* d_ws, size_t ws_size,
                              hipStream_t stream) {
    const float* img1 = (const float*)d_in[0];
    const float* img2 = (const float*)d_in[1];
    float* out = (float*)d_out;
    float* partials = (float*)d_ws;                  // 512 floats

    ssim_fused<<<512, 512, 0, stream>>>(img1, img2, partials);
    ssim_final<<<1, 256, 0, stream>>>(partials, 512, out,
                                      1.0 / ((double)S * 4));
}